// Round 14
// baseline (121.022 us; speedup 1.0000x reference)
//
#include <hip/hip_runtime.h>

// ============================================================================
// 7-layer MLP (3->40x6->3, tanh) via f16 MFMA, FULL-EXP tanh, ZERO LDS. (r14)
//
// r8-r13 evidence: dur pinned 112-121us; best = r8 (SEXP=6, most exp
// coverage, 111.6). Trend SEXP 6->3->2 = 111.6->114->116 CONTRADICTS the
// "trans blocks VALU 16cyc" model. New model: trans issue ~2cyc, executes on
// a separate quarter-rate pipe overlapped across waves -> exp path ~9 issue
// cyc/value, cheaper than table's ~10-11 VALU cyc + ds latency stalls +
// staging + syncthreads. r14 = decisive test: ALL tanh via exact
// t = 1 - 2*rcp(1+2^y) (weights pre-scaled 2/ln2), table deleted, LDS = 0,
// no barriers. Frags from global d_ws (L1-resident, r12-proven).
// Win case ~60-90us; >130 falsifies -> revert to r8 config.
//
// MFMA layout contracts (gfx950 v_mfma_f32_32x32x16_f16), verified r3-r13:
//   A: row = lane&31, k = 8*(lane>>5)+i   B: col = lane&31, same k packing
//   D: col = lane&31, row = (reg&3) + 8*(reg>>2) + 4*(lane>>5)
// K-columns permuted (kappa) so D->B repack is pure in-lane (verified:
// P := 4*(kap>>4)+((kap&7)>>1) == Bf word index for all 40 neurons).
// All hidden rows pre-scaled 2/ln2 -> MFMA emits y = 2x/ln2 directly; exp2
// overflow/underflow saturates rcp -> tanh = +-1 exactly (no clamp needed).
// Final layer scale 1.0, no activation. ws use = 35840 B (r6 ERRATA: stay
// well under ws_size; 64.6KB once overflowed and poisoned data).
// ============================================================================

typedef _Float16 f16x8 __attribute__((ext_vector_type(8)));
typedef float    f32x16 __attribute__((ext_vector_type(16)));
typedef unsigned int u32x4 __attribute__((ext_vector_type(4)));

#define NFRAG  35        // L0: 2, L1..5: 6 each, L6: 3
#define EXPSC  2.8853900817779268f   // 2/ln(2)

// k-slot -> input neuron; -2 = bias, -1 = zero pad
__constant__ int INV[48] = {
     0,  1,  2,  3,   8,  9, 10, 11,   4,  5,  6,  7,  12, 13, 14, 15,
    16, 17, 18, 19,  24, 25, 26, 27,  20, 21, 22, 23,  28, 29, 30, 31,
    32, 33, 34, 35,  -1, -1, -1, -1,  36, 37, 38, 39,  -2, -1, -1, -1 };

__global__ void prep_frags(const float* __restrict__ W0, const float* __restrict__ b0,
                           const float* __restrict__ W1, const float* __restrict__ b1,
                           const float* __restrict__ W2, const float* __restrict__ b2,
                           const float* __restrict__ W3, const float* __restrict__ b3,
                           const float* __restrict__ W4, const float* __restrict__ b4,
                           const float* __restrict__ W5, const float* __restrict__ b5,
                           const float* __restrict__ W6, const float* __restrict__ b6,
                           unsigned short* __restrict__ frags)
{
    int tid = blockIdx.x * 256 + threadIdx.x;
    if (tid >= NFRAG * 64) return;

    int frag = tid >> 6, lane = tid & 63;

    int layer, mt, ch;
    if (frag < 2)       { layer = 0; mt = frag; ch = 0; }
    else if (frag < 32) { int t = frag - 2; layer = 1 + t / 6; int r = t % 6; mt = r / 3; ch = r % 3; }
    else                { layer = 6; mt = 0; ch = frag - 32; }

    const float* Ws[7] = { W0, W1, W2, W3, W4, W5, W6 };
    const float* bs[7] = { b0, b1, b2, b3, b4, b5, b6 };
    const float* W = Ws[layer];
    const float* b = bs[layer];
    const int fout = (layer == 6) ? 3 : 40;
    const float scale = (layer == 6) ? 1.0f : EXPSC;   // MFMA emits y = 2x/ln2

    int jout  = mt * 32 + (lane & 31);
    int kbase = ch * 16 + (lane >> 5) * 8;

    unsigned short h[8];
    for (int i = 0; i < 8; ++i) {
        int k = kbase + i;
        float v = 0.0f;
        if (jout < fout) {
            int jin;
            if (layer == 0) jin = (k < 3) ? k : ((k == 3) ? -2 : -1);
            else            jin = INV[k];
            if (jin >= 0)       v = W[jin * fout + jout] * scale;
            else if (jin == -2) v = b[jout] * scale;
        }
        _Float16 hv = (_Float16)v;
        h[i] = __builtin_bit_cast(unsigned short, hv);
    }
    unsigned short* dst = frags + frag * 512 + lane * 8;
    for (int i = 0; i < 8; ++i) dst[i] = h[i];
}

__device__ __forceinline__ unsigned int pkf16(float a, float b) {
    return __builtin_bit_cast(unsigned int, __builtin_amdgcn_cvt_pkrtz(a, b));
}
__device__ __forceinline__ f32x16 zf() {
    f32x16 v;
    #pragma unroll
    for (int i = 0; i < 16; ++i) v[i] = 0.0f;
    return v;
}
__device__ __forceinline__ float exp2_fast(float y) {
#if __has_builtin(__builtin_amdgcn_exp2f)
    return __builtin_amdgcn_exp2f(y);
#else
    float e;
    asm("v_exp_f32 %0, %1" : "=v"(e) : "v"(y));
    return e;
#endif
}
__device__ __forceinline__ f16x8 mkf(unsigned a, unsigned b, unsigned c, unsigned d) {
    u32x4 t = { a, b, c, d };
    return __builtin_bit_cast(f16x8, t);
}

#define MFMA __builtin_amdgcn_mfma_f32_32x32x16_f16

// activation pack: 12 NAMED u32 fields (field-wise SROA, r11-proven)
struct BfT { unsigned w0, w1, w2, w3, w4, w5, w6, w7, w8, w9, w10, w11; };

#define BFC0(B) mkf((B).w0, (B).w1, (B).w2,  (B).w3)
#define BFC1(B) mkf((B).w4, (B).w5, (B).w6,  (B).w7)
#define BFC2(B) mkf((B).w8, (B).w9, (B).w10, (B).w11)

// all words via exact exp path
#define ACT_D1(Db, B) do {                            \
    (B).w8  = pkf16(te(Db[0]), te(Db[1]));            \
    (B).w9  = pkf16(te(Db[2]), te(Db[3]));            \
    (B).w10 = PK11;                                   \
    (B).w11 = 0u;                                     \
} while (0)

#define ACT_D0(Da, B) do {                            \
    (B).w0 = pkf16(te(Da[0]),  te(Da[1]));            \
    (B).w1 = pkf16(te(Da[2]),  te(Da[3]));            \
    (B).w2 = pkf16(te(Da[4]),  te(Da[5]));            \
    (B).w3 = pkf16(te(Da[6]),  te(Da[7]));            \
    (B).w4 = pkf16(te(Da[8]),  te(Da[9]));            \
    (B).w5 = pkf16(te(Da[10]), te(Da[11]));           \
    (B).w6 = pkf16(te(Da[12]), te(Da[13]));           \
    (B).w7 = pkf16(te(Da[14]), te(Da[15]));           \
} while (0)

// one 32-point tile of layer 0 (K chunk 0: coords + bias col)
#define L0_TILE(B) do {                               \
    f16x8 bb = BFC0(B);                               \
    {                                                 \
        f32x16 D1 = MFMA(F1, bb, CZ, 0, 0, 0);        \
        ACT_D1(D1, B);                                \
    }                                                 \
    {                                                 \
        f32x16 D0 = MFMA(F0, bb, CZ, 0, 0, 0);        \
        ACT_D0(D0, B);                                \
    }                                                 \
} while (0)

// one 32-point tile of a hidden layer (D1 first, then D0)
#define HID_TILE(B) do {                              \
    f16x8 B0 = BFC0(B), B1 = BFC1(B), B2 = BFC2(B);   \
    {                                                 \
        f32x16 D1 = MFMA(F3, B0, CZ, 0, 0, 0);        \
        D1 = MFMA(F4, B1, D1, 0, 0, 0);               \
        D1 = MFMA(F5, B2, D1, 0, 0, 0);               \
        ACT_D1(D1, B);                                \
    }                                                 \
    {                                                 \
        f32x16 D0 = MFMA(F0, B0, CZ, 0, 0, 0);        \
        D0 = MFMA(F1, B1, D0, 0, 0, 0);               \
        D0 = MFMA(F2, B2, D0, 0, 0, 0);               \
        ACT_D0(D0, B);                                \
    }                                                 \
} while (0)

// one 32-point tile of the final layer (rows 0..2, lane<32)
#define FIN_TILE(B, pX, vX) do {                      \
    f32x16 D0 = MFMA(F0, BFC0(B), CZ, 0, 0, 0);       \
    D0 = MFMA(F1, BFC1(B), D0, 0, 0, 0);              \
    D0 = MFMA(F2, BFC2(B), D0, 0, 0, 0);              \
    if (lane < 32 && vX) {                            \
        out[(pX) * 3 + 0] = D0[0];                    \
        out[(pX) * 3 + 1] = D0[1];                    \
        out[(pX) * 3 + 2] = D0[2];                    \
    }                                                 \
} while (0)

__global__ __launch_bounds__(256) void mlp_mfma(const float* __restrict__ coords,
                                                const unsigned short* __restrict__ frags,
                                                float* __restrict__ out, int npts)
{
    // ZERO LDS, zero barriers (r14)
    const int lane = threadIdx.x & 63;
    const int wid  = threadIdx.x >> 6;
    const int pA   = (blockIdx.x * 4 + wid) * 64 + (lane & 31);
    const int pB   = pA + 32;
    const bool vA = (pA < npts), vB = (pB < npts);

    const unsigned int PK11 = pkf16(1.0f, 1.0f);
    const f32x16 CZ = zf();

    // exact tanh: y = 2x/ln2 from pre-scaled weights; t = 1 - 2/(1+2^y).
    // 2^y -> inf gives rcp->0 -> +1; 2^y -> 0 gives rcp(1)=1 -> -1.
    auto te = [&](float y) -> float {
        float e = exp2_fast(y);
        float r = __builtin_amdgcn_rcpf(e + 1.0f);
        return __builtin_fmaf(-2.0f, r, 1.0f);
    };

    BfT A, B;
    {
        float a0 = 0.f, a1 = 0.f, a2 = 0.f, b0 = 0.f, b1 = 0.f, b2 = 0.f;
        if (vA) { a0 = coords[pA * 3]; a1 = coords[pA * 3 + 1]; a2 = coords[pA * 3 + 2]; }
        if (vB) { b0 = coords[pB * 3]; b1 = coords[pB * 3 + 1]; b2 = coords[pB * 3 + 2]; }
        A.w0 = pkf16(a0, a1); A.w1 = pkf16(a2, 1.0f);
        B.w0 = pkf16(b0, b1); B.w1 = pkf16(b2, 1.0f);
        A.w2 = B.w2 = 0u;
        A.w3 = B.w3 = 0u;
    }

    // weight fragments from GLOBAL (d_ws): per-lane coalesced 16B loads,
    // same addresses for every wave -> L1/L2-resident (35 KB total)
    auto AF = [&](int f) -> f16x8 {
        return ((const f16x8*)frags)[f * 64 + lane];
    };

    f16x8 F0, F1, F2, F3, F4, F5;

    // ---- layer 0
    F0 = AF(0); F1 = AF(1);
    L0_TILE(A); L0_TILE(B);

    // ---- hidden layers 1..5
    #pragma unroll
    for (int l = 1; l <= 5; ++l) {
        const int fb = 2 + (l - 1) * 6;
        F0 = AF(fb + 0); F1 = AF(fb + 1); F2 = AF(fb + 2);
        F3 = AF(fb + 3); F4 = AF(fb + 4); F5 = AF(fb + 5);
        HID_TILE(A); HID_TILE(B);
    }

    // ---- layer 6: [40] -> [3], true scale, no tanh
    F0 = AF(32); F1 = AF(33); F2 = AF(34);
    FIN_TILE(A, pA, vA);
    FIN_TILE(B, pB, vB);
}

extern "C" void kernel_launch(void* const* d_in, const int* in_sizes, int n_in,
                              void* d_out, int out_size, void* d_ws, size_t ws_size,
                              hipStream_t stream)
{
    const float* coords = (const float*)d_in[0];
    const float* W0 = (const float*)d_in[1];  const float* b0 = (const float*)d_in[2];
    const float* W1 = (const float*)d_in[3];  const float* b1 = (const float*)d_in[4];
    const float* W2 = (const float*)d_in[5];  const float* b2 = (const float*)d_in[6];
    const float* W3 = (const float*)d_in[7];  const float* b3 = (const float*)d_in[8];
    const float* W4 = (const float*)d_in[9];  const float* b4 = (const float*)d_in[10];
    const float* W5 = (const float*)d_in[11]; const float* b5 = (const float*)d_in[12];
    const float* W6 = (const float*)d_in[13]; const float* b6 = (const float*)d_in[14];
    float* out = (float*)d_out;

    unsigned short* frags = (unsigned short*)d_ws;                      // 35840 B

    const int npts = in_sizes[0] / 3;

    prep_frags<<<(NFRAG * 64 + 255) / 256, 256, 0, stream>>>(
        W0, b0, W1, b1, W2, b2, W3, b3, W4, b4, W5, b5, W6, b6, frags);

    const int blocks = (npts + 255) / 256;   // 256 points per block (4 waves x 64)
    mlp_mfma<<<blocks, 256, 0, stream>>>(coords, frags, out, npts);
}

// Round 15
// 119.129 us; speedup vs baseline: 1.0159x; 1.0159x over previous
//
#include <hip/hip_runtime.h>

// ============================================================================
// 7-layer MLP (3->40x6->3, tanh) via f16 MFMA + dual-pipe tanh. (r15)
//
// r15 = r8 champion (111.6us: SEXP=6, 2 tiles, frags+table in LDS) with ONE
// change: #pragma unroll 1 on the hidden-layer loop. Theory: every r7-r14
// variant ships a fully-unrolled ~20-30KB straight-line body; mixes sit
// 30-40us above their pipe-sum models with 25-30% VALU idle that neither
// phase-split (r13) nor occupancy (r12) nor structure (r9-r11) recovers.
// Candidate wall: L1I fetch on straight-line code (zero instruction reuse
// per wave, thrash when waves de-phase). Rolling the loop shrinks code ~3x
// and re-executes a hot ~2KB body 5x.
// WIN (>=10us) -> code-size path continues. NEUTRAL -> plateau is
// latency-structural; VALU-issue floor ~100us => within ~12% of wall.
//
// Pipe model (fit r3-r14): trans ~16cyc/wave64-op on the per-SIMD issue
// budget; table tanh ~13-17 VALU cyc + 5.8 LDS cyc (per-CU pipe); pure-exp
// r14 = 124us model vs 121 measured; pure-table r7 LDS-bound 97 vs 119.
//
// MFMA layout contracts (gfx950 v_mfma_f32_32x32x16_f16), verified r3-r14:
//   A: row = lane&31, k = 8*(lane>>5)+i   B: col = lane&31, same k packing
//   D: col = lane&31, row = (reg&3) + 8*(reg>>2) + 4*(lane>>5)
// K-columns permuted (kappa) so D->B repack is in-lane. Verified identity:
// P := 4*(kap>>4) + ((kap&7)>>1) == Bf word index, all 40 neurons.
// Exp rows (words 0..5) pre-scaled 2/ln2: tanh = 1-2*rcp(1+2^y), exact.
// Table rows pre-scaled 32 + offset col 112 (MFMA emits u = (x+3.5)*32).
// Table: 225 entries, packed f16 {base,delta}/u32, 32-replica in LDS ->
// bank == lane&31 -> conflict-free (verified r7: conflicts 1.6e7 -> 0).
// ws = 36.7 KB total (r6 ERRATA: 64.6 KB overflowed ws -> poisoned table).
// ============================================================================

typedef _Float16 f16x8 __attribute__((ext_vector_type(8)));
typedef float    f32x16 __attribute__((ext_vector_type(16)));
typedef unsigned int u32x4 __attribute__((ext_vector_type(4)));

#define NFRAG  35        // L0: 2, L1..5: 6 each, L6: 3
#define TABN   225       // entries, domain [-3.5, 3.5], h = 1/32
#define TABREP 32        // LDS replication -> bank = lane&31, conflict-free
#define SEXP   6         // Bf words 0..5 (24 rows/layer) via exp path
#define INVH   32.0f
#define UOFF   112.0f    // 3.5*32, exact in f16
#define UMAX   223.999f
#define TABR   3.5f
#define EXPSC  2.8853900817779268f   // 2/ln(2)

// k-slot -> input neuron; -2 = bias, -3 = offset const, -1 = zero pad
__constant__ int INV[48] = {
     0,  1,  2,  3,   8,  9, 10, 11,   4,  5,  6,  7,  12, 13, 14, 15,
    16, 17, 18, 19,  24, 25, 26, 27,  20, 21, 22, 23,  28, 29, 30, 31,
    32, 33, 34, 35,  -1, -1, -1, -1,  36, 37, 38, 39,  -2, -3, -1, -1 };

// output neuron j -> k-slot (kappa); P(j) = 4*(kap>>4) + ((kap&7)>>1) = word
__constant__ int KAP[40] = {
     0,  1,  2,  3,   8,  9, 10, 11,   4,  5,  6,  7,  12, 13, 14, 15,
    16, 17, 18, 19,  24, 25, 26, 27,  20, 21, 22, 23,  28, 29, 30, 31,
    32, 33, 34, 35,  40, 41, 42, 43 };

__global__ void prep_frags(const float* __restrict__ W0, const float* __restrict__ b0,
                           const float* __restrict__ W1, const float* __restrict__ b1,
                           const float* __restrict__ W2, const float* __restrict__ b2,
                           const float* __restrict__ W3, const float* __restrict__ b3,
                           const float* __restrict__ W4, const float* __restrict__ b4,
                           const float* __restrict__ W5, const float* __restrict__ b5,
                           const float* __restrict__ W6, const float* __restrict__ b6,
                           unsigned short* __restrict__ frags,
                           unsigned* __restrict__ table)
{
    int tid = blockIdx.x * 256 + threadIdx.x;

    if (tid < NFRAG * 64) {
        int frag = tid >> 6, lane = tid & 63;

        int layer, mt, ch;
        if (frag < 2)       { layer = 0; mt = frag; ch = 0; }
        else if (frag < 32) { int t = frag - 2; layer = 1 + t / 6; int r = t % 6; mt = r / 3; ch = r % 3; }
        else                { layer = 6; mt = 0; ch = frag - 32; }

        const float* Ws[7] = { W0, W1, W2, W3, W4, W5, W6 };
        const float* bs[7] = { b0, b1, b2, b3, b4, b5, b6 };
        const float* W = Ws[layer];
        const float* b = bs[layer];
        const int fout = (layer == 6) ? 3 : 40;

        int jout  = mt * 32 + (lane & 31);
        int kbase = ch * 16 + (lane >> 5) * 8;

        unsigned short h[8];
        for (int i = 0; i < 8; ++i) {
            int k = kbase + i;
            float v = 0.0f;
            if (jout < fout) {
                int jin;
                if (layer == 0) jin = (k < 3) ? k : ((k == 3) ? -2 : ((k == 4) ? -3 : -1));
                else            jin = INV[k];
                bool ex = false;
                if (layer < 6) {
                    int kp = KAP[jout];
                    int P = 4 * (kp >> 4) + ((kp & 7) >> 1);   // == Bf word index
                    ex = (P < SEXP);
                }
                float scale = (layer == 6) ? 1.0f : (ex ? EXPSC : INVH);
                if (jin >= 0)       v = W[jin * fout + jout] * scale;
                else if (jin == -2) v = b[jout] * scale;
                else if (jin == -3) v = (layer == 6 || ex) ? 0.0f : UOFF;
            }
            _Float16 hv = (_Float16)v;
            h[i] = __builtin_bit_cast(unsigned short, hv);
        }
        unsigned short* dst = frags + frag * 512 + lane * 8;
        for (int i = 0; i < 8; ++i) dst[i] = h[i];
    }
    else if (tid < NFRAG * 64 + TABN) {
        int i = tid - NFRAG * 64;
        const float H = 1.0f / 32.0f;
        float x  = -TABR + (float)i * H;
        float t0 = tanhf(x);
        float t1 = tanhf(x + H);
        float MID = 0.5f * (1.0f + tanhf(TABR));
        float base = t0, delta = t1 - t0;
        if (i == 0)        { base = -MID; delta = t1 - base; }   // left clamp midpoint
        if (i == TABN - 2) { delta = MID - t0; }                 // right clamp midpoint
        unsigned short bb = __builtin_bit_cast(unsigned short, (_Float16)base);
        unsigned short dd = __builtin_bit_cast(unsigned short, (_Float16)delta);
        table[i] = (unsigned)bb | ((unsigned)dd << 16);          // unreplicated, 900 B
    }
}

__device__ __forceinline__ unsigned int pkf16(float a, float b) {
    return __builtin_bit_cast(unsigned int, __builtin_amdgcn_cvt_pkrtz(a, b));
}
__device__ __forceinline__ f32x16 zf() {
    f32x16 v;
    #pragma unroll
    for (int i = 0; i < 16; ++i) v[i] = 0.0f;
    return v;
}
__device__ __forceinline__ float exp2_fast(float y) {
#if __has_builtin(__builtin_amdgcn_exp2f)
    return __builtin_amdgcn_exp2f(y);
#else
    float e;
    asm("v_exp_f32 %0, %1" : "=v"(e) : "v"(y));
    return e;
#endif
}

#define MFMA __builtin_amdgcn_mfma_f32_32x32x16_f16

// words 0..5: exp path (y = 2x/ln2 from MFMA); words 6..9: table path
#define ACT(Da, Db, Bfx) do {                         \
    Bfx[0]  = pkf16(te(Da[0]),  te(Da[1]));           \
    Bfx[1]  = pkf16(te(Da[2]),  te(Da[3]));           \
    Bfx[2]  = pkf16(te(Da[4]),  te(Da[5]));           \
    Bfx[3]  = pkf16(te(Da[6]),  te(Da[7]));           \
    Bfx[4]  = pkf16(te(Da[8]),  te(Da[9]));           \
    Bfx[5]  = pkf16(te(Da[10]), te(Da[11]));          \
    Bfx[6]  = tl2(Da[12], Da[13]);                    \
    Bfx[7]  = tl2(Da[14], Da[15]);                    \
    Bfx[8]  = tl2(Db[0],  Db[1]);                     \
    Bfx[9]  = tl2(Db[2],  Db[3]);                     \
    Bfx[10] = PK11;                                   \
    Bfx[11] = 0u;                                     \
} while (0)

__global__ __launch_bounds__(512, 4) void mlp_mfma(const float* __restrict__ coords,
                                                   const unsigned short* __restrict__ frags,
                                                   const unsigned* __restrict__ gtab,
                                                   float* __restrict__ out, int npts)
{
    __shared__ __align__(16) unsigned short sf[NFRAG * 512];   // 35840 B
    __shared__ __align__(16) unsigned stab[TABN * TABREP];     // 28800 B
    {
        const u32x4* s1 = (const u32x4*)frags; u32x4* d1 = (u32x4*)sf;
        for (int i = threadIdx.x; i < NFRAG * 64; i += 512) d1[i] = s1[i];
        // replicate 32x from the unreplicated global table (L2-resident)
        for (int i = threadIdx.x; i < TABN * TABREP; i += 512) stab[i] = gtab[i >> 5];
    }
    __syncthreads();

    const int lane = threadIdx.x & 63;
    const int wid  = threadIdx.x >> 6;
    const int pA   = (blockIdx.x * 8 + wid) * 64 + (lane & 31);
    const int pB   = pA + 32;
    const bool vA = (pA < npts), vB = (pB < npts);

    float cA0 = 0.f, cA1 = 0.f, cA2 = 0.f, cB0 = 0.f, cB1 = 0.f, cB2 = 0.f;
    if (vA) { cA0 = coords[pA * 3]; cA1 = coords[pA * 3 + 1]; cA2 = coords[pA * 3 + 2]; }
    if (vB) { cB0 = coords[pB * 3]; cB1 = coords[pB * 3 + 1]; cB2 = coords[pB * 3 + 2]; }

    const unsigned int PK11 = pkf16(1.0f, 1.0f);
    const unsigned* __restrict__ tb = stab + (lane & 31);   // bank = lane&31 always
    const f32x16 CZ = zf();

    // table path: u = (x+3.5)*32 from MFMA; {base,delta} packed f16 in u32.
    auto tl2 = [&](float ua, float ub) -> unsigned {
        ua = __builtin_amdgcn_fmed3f(ua, 0.0f, UMAX);
        ub = __builtin_amdgcn_fmed3f(ub, 0.0f, UMAX);
        float fa = __builtin_amdgcn_fractf(ua);
        float fb = __builtin_amdgcn_fractf(ub);
        unsigned ea = tb[(unsigned)ua * TABREP];   // ds_read_b32, conflict-free
        unsigned eb = tb[(unsigned)ub * TABREP];
        unsigned r;
        asm("v_fma_mixlo_f16 %0, %1, %2, %2 op_sel:[0,1,0] op_sel_hi:[0,1,1]"
            : "=v"(r) : "v"(fa), "v"(ea));
        asm("v_fma_mixhi_f16 %0, %1, %2, %2 op_sel:[0,1,0] op_sel_hi:[0,1,1]"
            : "+v"(r) : "v"(fb), "v"(eb));
        return r;
    };
    // exp path: y = 2x/ln2 from MFMA; tanh = 1 - 2/(1+2^y). Exact, no clamp:
    // 2^y -> inf gives rcp->0 -> +1; 2^y -> 0 gives rcp(1)=1 -> -1.
    auto te = [&](float y) -> float {
        float e = exp2_fast(y);
        float r = __builtin_amdgcn_rcpf(e + 1.0f);
        return __builtin_fmaf(-2.0f, r, 1.0f);
    };

    unsigned int BfA[12], BfB[12];
    BfA[0] = pkf16(cA0, cA1); BfA[1] = pkf16(cA2, 1.0f);
    BfA[2] = pkf16(1.0f, 0.0f); BfA[3] = 0u;
    BfB[0] = pkf16(cB0, cB1); BfB[1] = pkf16(cB2, 1.0f);
    BfB[2] = pkf16(1.0f, 0.0f); BfB[3] = 0u;

    auto AF = [&](int f) -> f16x8 {
        return ((const f16x8*)sf)[f * 64 + lane];
    };
    auto BFx = [&](const unsigned (&B)[12], int c) -> f16x8 {
        u32x4 t = { B[4 * c + 0], B[4 * c + 1], B[4 * c + 2], B[4 * c + 3] };
        return __builtin_bit_cast(f16x8, t);
    };

    f16x8 F0, F1, F2, F3, F4, F5;

    // ---- layer 0 (K chunk 0: coords + bias + offset cols)
    F0 = AF(0); F1 = AF(1);
    {
        f32x16 D0 = MFMA(F0, BFx(BfA, 0), CZ, 0, 0, 0);
        f32x16 D1 = MFMA(F1, BFx(BfA, 0), CZ, 0, 0, 0);
        ACT(D0, D1, BfA);
    }
    {
        f32x16 D0 = MFMA(F0, BFx(BfB, 0), CZ, 0, 0, 0);
        f32x16 D1 = MFMA(F1, BFx(BfB, 0), CZ, 0, 0, 0);
        ACT(D0, D1, BfB);
    }

    // ---- hidden layers 1..5: ROLLED (r15: the single change vs r8).
    // Body executes 5x from hot I-cache instead of 5x straight-line code.
    #pragma unroll 1
    for (int l = 1; l <= 5; ++l) {
        const int fb = 2 + (l - 1) * 6;
        F0 = AF(fb + 0); F1 = AF(fb + 1); F2 = AF(fb + 2);
        F3 = AF(fb + 3); F4 = AF(fb + 4); F5 = AF(fb + 5);
        {
            f16x8 B0 = BFx(BfA, 0), B1 = BFx(BfA, 1), B2 = BFx(BfA, 2);
            f32x16 D0 = MFMA(F0, B0, CZ, 0, 0, 0);
            D0 = MFMA(F1, B1, D0, 0, 0, 0);
            D0 = MFMA(F2, B2, D0, 0, 0, 0);
            f32x16 D1 = MFMA(F3, B0, CZ, 0, 0, 0);
            D1 = MFMA(F4, B1, D1, 0, 0, 0);
            D1 = MFMA(F5, B2, D1, 0, 0, 0);
            ACT(D0, D1, BfA);
        }
        {
            f16x8 B0 = BFx(BfB, 0), B1 = BFx(BfB, 1), B2 = BFx(BfB, 2);
            f32x16 D0 = MFMA(F0, B0, CZ, 0, 0, 0);
            D0 = MFMA(F1, B1, D0, 0, 0, 0);
            D0 = MFMA(F2, B2, D0, 0, 0, 0);
            f32x16 D1 = MFMA(F3, B0, CZ, 0, 0, 0);
            D1 = MFMA(F4, B1, D1, 0, 0, 0);
            D1 = MFMA(F5, B2, D1, 0, 0, 0);
            ACT(D0, D1, BfB);
        }
    }

    // ---- layer 6: [40] -> [3], true scale, no tanh. Rows 0..2 (lane<32).
    F0 = AF(32); F1 = AF(33); F2 = AF(34);
    {
        f32x16 D0 = MFMA(F0, BFx(BfA, 0), CZ, 0, 0, 0);
        D0 = MFMA(F1, BFx(BfA, 1), D0, 0, 0, 0);
        D0 = MFMA(F2, BFx(BfA, 2), D0, 0, 0, 0);
        if (lane < 32 && vA) {
            out[pA * 3 + 0] = D0[0];
            out[pA * 3 + 1] = D0[1];
            out[pA * 3 + 2] = D0[2];
        }
    }
    {
        f32x16 D0 = MFMA(F0, BFx(BfB, 0), CZ, 0, 0, 0);
        D0 = MFMA(F1, BFx(BfB, 1), D0, 0, 0, 0);
        D0 = MFMA(F2, BFx(BfB, 2), D0, 0, 0, 0);
        if (lane < 32 && vB) {
            out[pB * 3 + 0] = D0[0];
            out[pB * 3 + 1] = D0[1];
            out[pB * 3 + 2] = D0[2];
        }
    }
}

extern "C" void kernel_launch(void* const* d_in, const int* in_sizes, int n_in,
                              void* d_out, int out_size, void* d_ws, size_t ws_size,
                              hipStream_t stream)
{
    const float* coords = (const float*)d_in[0];
    const float* W0 = (const float*)d_in[1];  const float* b0 = (const float*)d_in[2];
    const float* W1 = (const float*)d_in[3];  const float* b1 = (const float*)d_in[4];
    const float* W2 = (const float*)d_in[5];  const float* b2 = (const float*)d_in[6];
    const float* W3 = (const float*)d_in[7];  const float* b3 = (const float*)d_in[8];
    const float* W4 = (const float*)d_in[9];  const float* b4 = (const float*)d_in[10];
    const float* W5 = (const float*)d_in[11]; const float* b5 = (const float*)d_in[12];
    const float* W6 = (const float*)d_in[13]; const float* b6 = (const float*)d_in[14];
    float* out = (float*)d_out;

    unsigned short* frags = (unsigned short*)d_ws;                      // 35840 B
    unsigned* table = (unsigned*)((char*)d_ws + NFRAG * 1024);          // 900 B

    const int npts = in_sizes[0] / 3;

    const int prep_threads = NFRAG * 64 + TABN;
    prep_frags<<<(prep_threads + 255) / 256, 256, 0, stream>>>(
        W0, b0, W1, b1, W2, b2, W3, b3, W4, b4, W5, b5, W6, b6, frags, table);

    const int blocks = (npts + 511) / 512;   // 512 points per block (8 waves x 64)
    mlp_mfma<<<blocks, 512, 0, stream>>>(coords, frags, table, out, npts);
}

// Round 16
// 112.195 us; speedup vs baseline: 1.0787x; 1.0618x over previous
//
#include <hip/hip_runtime.h>

// ============================================================================
// 7-layer MLP (3->40x6->3, tanh) via f16 MFMA + dual-pipe tanh. (r16 = r8)
//
// CHAMPION RESTORE: r8 config verbatim (111.6us measured). Ablation matrix
// r8-r15 (eight structural variants) all landed 112-121us:
//   occupancy 2x (r12) neutral; tiles 2/3/4 neutral; frags LDS<->global
//   neutral; SEXP 2/3/6 -> 116/114/111.6 (6 best); phase-split waitcnt
//   batching neutral; zero-LDS full-exp 121 (trans-issue-bound, model 124);
//   rolled loop 119. Conclusion: activation-issue-bound. 240 tanh/wave
//   through the per-SIMD issue port = ~84-99us busy at 32 waves/SIMD;
//   SEXP=6 is the empirical optimum of the VALU-issue vs LDS-pipe trade.
//   MFMA 24%, HBM 3.5%, conflicts 0, spill 0 -> no other pipe to shift to.
//
// words 0..5 of each activation pack (24/40 neurons): EXACT exp path
//   t = 1 - 2*rcp(1+2^y), weights pre-scaled by 2/ln2 -> MFMA emits y.
// words 6..9 (16/40 neurons): conflict-free LDS lerp table (32-replica,
//   bank == lane&31 always). Weights pre-scaled by 32 + offset column 112.
//
// MFMA layout contracts (gfx950 v_mfma_f32_32x32x16_f16), verified r3-r15:
//   A: row = lane&31, k = 8*(lane>>5)+i   B: col = lane&31, same k packing
//   D: col = lane&31, row = (reg&3) + 8*(reg>>2) + 4*(lane>>5)
// K-columns permuted (kappa) so D->B repack is in-lane. Verified identity:
// P := 4*(kap>>4) + ((kap&7)>>1) == Bf word index, all 40 neurons.
// Table: 225 entries, packed f16 {base,delta}/u32, 32x replicated in LDS.
// ws = 36.7 KB total (r6 ERRATA: 64.6 KB overflowed ws -> poisoned table).
// ============================================================================

typedef _Float16 f16x8 __attribute__((ext_vector_type(8)));
typedef float    f32x16 __attribute__((ext_vector_type(16)));
typedef unsigned int u32x4 __attribute__((ext_vector_type(4)));

#define NFRAG  35        // L0: 2, L1..5: 6 each, L6: 3
#define TABN   225       // entries, domain [-3.5, 3.5], h = 1/32
#define TABREP 32        // LDS replication -> bank = lane&31, conflict-free
#define SEXP   6         // Bf words 0..5 (24 rows/layer) via exp path
#define INVH   32.0f
#define UOFF   112.0f    // 3.5*32, exact in f16
#define UMAX   223.999f
#define TABR   3.5f
#define EXPSC  2.8853900817779268f   // 2/ln(2)

// k-slot -> input neuron; -2 = bias, -3 = offset const, -1 = zero pad
__constant__ int INV[48] = {
     0,  1,  2,  3,   8,  9, 10, 11,   4,  5,  6,  7,  12, 13, 14, 15,
    16, 17, 18, 19,  24, 25, 26, 27,  20, 21, 22, 23,  28, 29, 30, 31,
    32, 33, 34, 35,  -1, -1, -1, -1,  36, 37, 38, 39,  -2, -3, -1, -1 };

// output neuron j -> k-slot (kappa); P(j) = 4*(kap>>4) + ((kap&7)>>1) = word
__constant__ int KAP[40] = {
     0,  1,  2,  3,   8,  9, 10, 11,   4,  5,  6,  7,  12, 13, 14, 15,
    16, 17, 18, 19,  24, 25, 26, 27,  20, 21, 22, 23,  28, 29, 30, 31,
    32, 33, 34, 35,  40, 41, 42, 43 };

__global__ void prep_frags(const float* __restrict__ W0, const float* __restrict__ b0,
                           const float* __restrict__ W1, const float* __restrict__ b1,
                           const float* __restrict__ W2, const float* __restrict__ b2,
                           const float* __restrict__ W3, const float* __restrict__ b3,
                           const float* __restrict__ W4, const float* __restrict__ b4,
                           const float* __restrict__ W5, const float* __restrict__ b5,
                           const float* __restrict__ W6, const float* __restrict__ b6,
                           unsigned short* __restrict__ frags,
                           unsigned* __restrict__ table)
{
    int tid = blockIdx.x * 256 + threadIdx.x;

    if (tid < NFRAG * 64) {
        int frag = tid >> 6, lane = tid & 63;

        int layer, mt, ch;
        if (frag < 2)       { layer = 0; mt = frag; ch = 0; }
        else if (frag < 32) { int t = frag - 2; layer = 1 + t / 6; int r = t % 6; mt = r / 3; ch = r % 3; }
        else                { layer = 6; mt = 0; ch = frag - 32; }

        const float* Ws[7] = { W0, W1, W2, W3, W4, W5, W6 };
        const float* bs[7] = { b0, b1, b2, b3, b4, b5, b6 };
        const float* W = Ws[layer];
        const float* b = bs[layer];
        const int fout = (layer == 6) ? 3 : 40;

        int jout  = mt * 32 + (lane & 31);
        int kbase = ch * 16 + (lane >> 5) * 8;

        unsigned short h[8];
        for (int i = 0; i < 8; ++i) {
            int k = kbase + i;
            float v = 0.0f;
            if (jout < fout) {
                int jin;
                if (layer == 0) jin = (k < 3) ? k : ((k == 3) ? -2 : ((k == 4) ? -3 : -1));
                else            jin = INV[k];
                bool ex = false;
                if (layer < 6) {
                    int kp = KAP[jout];
                    int P = 4 * (kp >> 4) + ((kp & 7) >> 1);   // == Bf word index
                    ex = (P < SEXP);
                }
                float scale = (layer == 6) ? 1.0f : (ex ? EXPSC : INVH);
                if (jin >= 0)       v = W[jin * fout + jout] * scale;
                else if (jin == -2) v = b[jout] * scale;
                else if (jin == -3) v = (layer == 6 || ex) ? 0.0f : UOFF;
            }
            _Float16 hv = (_Float16)v;
            h[i] = __builtin_bit_cast(unsigned short, hv);
        }
        unsigned short* dst = frags + frag * 512 + lane * 8;
        for (int i = 0; i < 8; ++i) dst[i] = h[i];
    }
    else if (tid < NFRAG * 64 + TABN) {
        int i = tid - NFRAG * 64;
        const float H = 1.0f / 32.0f;
        float x  = -TABR + (float)i * H;
        float t0 = tanhf(x);
        float t1 = tanhf(x + H);
        float MID = 0.5f * (1.0f + tanhf(TABR));
        float base = t0, delta = t1 - t0;
        if (i == 0)        { base = -MID; delta = t1 - base; }   // left clamp midpoint
        if (i == TABN - 2) { delta = MID - t0; }                 // right clamp midpoint
        unsigned short bb = __builtin_bit_cast(unsigned short, (_Float16)base);
        unsigned short dd = __builtin_bit_cast(unsigned short, (_Float16)delta);
        table[i] = (unsigned)bb | ((unsigned)dd << 16);          // unreplicated, 900 B
    }
}

__device__ __forceinline__ unsigned int pkf16(float a, float b) {
    return __builtin_bit_cast(unsigned int, __builtin_amdgcn_cvt_pkrtz(a, b));
}
__device__ __forceinline__ f32x16 zf() {
    f32x16 v;
    #pragma unroll
    for (int i = 0; i < 16; ++i) v[i] = 0.0f;
    return v;
}
__device__ __forceinline__ float exp2_fast(float y) {
#if __has_builtin(__builtin_amdgcn_exp2f)
    return __builtin_amdgcn_exp2f(y);
#else
    float e;
    asm("v_exp_f32 %0, %1" : "=v"(e) : "v"(y));
    return e;
#endif
}

#define MFMA __builtin_amdgcn_mfma_f32_32x32x16_f16

// words 0..5: exp path (y = 2x/ln2 from MFMA); words 6..9: table path
#define ACT(Da, Db, Bfx) do {                         \
    Bfx[0]  = pkf16(te(Da[0]),  te(Da[1]));           \
    Bfx[1]  = pkf16(te(Da[2]),  te(Da[3]));           \
    Bfx[2]  = pkf16(te(Da[4]),  te(Da[5]));           \
    Bfx[3]  = pkf16(te(Da[6]),  te(Da[7]));           \
    Bfx[4]  = pkf16(te(Da[8]),  te(Da[9]));           \
    Bfx[5]  = pkf16(te(Da[10]), te(Da[11]));          \
    Bfx[6]  = tl2(Da[12], Da[13]);                    \
    Bfx[7]  = tl2(Da[14], Da[15]);                    \
    Bfx[8]  = tl2(Db[0],  Db[1]);                     \
    Bfx[9]  = tl2(Db[2],  Db[3]);                     \
    Bfx[10] = PK11;                                   \
    Bfx[11] = 0u;                                     \
} while (0)

__global__ __launch_bounds__(512, 4) void mlp_mfma(const float* __restrict__ coords,
                                                   const unsigned short* __restrict__ frags,
                                                   const unsigned* __restrict__ gtab,
                                                   float* __restrict__ out, int npts)
{
    __shared__ __align__(16) unsigned short sf[NFRAG * 512];   // 35840 B
    __shared__ __align__(16) unsigned stab[TABN * TABREP];     // 28800 B
    {
        const u32x4* s1 = (const u32x4*)frags; u32x4* d1 = (u32x4*)sf;
        for (int i = threadIdx.x; i < NFRAG * 64; i += 512) d1[i] = s1[i];
        // replicate 32x from the unreplicated global table (L2-resident)
        for (int i = threadIdx.x; i < TABN * TABREP; i += 512) stab[i] = gtab[i >> 5];
    }
    __syncthreads();

    const int lane = threadIdx.x & 63;
    const int wid  = threadIdx.x >> 6;
    const int pA   = (blockIdx.x * 8 + wid) * 64 + (lane & 31);
    const int pB   = pA + 32;
    const bool vA = (pA < npts), vB = (pB < npts);

    float cA0 = 0.f, cA1 = 0.f, cA2 = 0.f, cB0 = 0.f, cB1 = 0.f, cB2 = 0.f;
    if (vA) { cA0 = coords[pA * 3]; cA1 = coords[pA * 3 + 1]; cA2 = coords[pA * 3 + 2]; }
    if (vB) { cB0 = coords[pB * 3]; cB1 = coords[pB * 3 + 1]; cB2 = coords[pB * 3 + 2]; }

    const unsigned int PK11 = pkf16(1.0f, 1.0f);
    const unsigned* __restrict__ tb = stab + (lane & 31);   // bank = lane&31 always
    const f32x16 CZ = zf();

    // table path: u = (x+3.5)*32 from MFMA; {base,delta} packed f16 in u32.
    auto tl2 = [&](float ua, float ub) -> unsigned {
        ua = __builtin_amdgcn_fmed3f(ua, 0.0f, UMAX);
        ub = __builtin_amdgcn_fmed3f(ub, 0.0f, UMAX);
        float fa = __builtin_amdgcn_fractf(ua);
        float fb = __builtin_amdgcn_fractf(ub);
        unsigned ea = tb[(unsigned)ua * TABREP];   // ds_read_b32, conflict-free
        unsigned eb = tb[(unsigned)ub * TABREP];
        unsigned r;
        asm("v_fma_mixlo_f16 %0, %1, %2, %2 op_sel:[0,1,0] op_sel_hi:[0,1,1]"
            : "=v"(r) : "v"(fa), "v"(ea));
        asm("v_fma_mixhi_f16 %0, %1, %2, %2 op_sel:[0,1,0] op_sel_hi:[0,1,1]"
            : "+v"(r) : "v"(fb), "v"(eb));
        return r;
    };
    // exp path: y = 2x/ln2 from MFMA; tanh = 1 - 2/(1+2^y). Exact, no clamp:
    // 2^y -> inf gives rcp->0 -> +1; 2^y -> 0 gives rcp(1)=1 -> -1.
    auto te = [&](float y) -> float {
        float e = exp2_fast(y);
        float r = __builtin_amdgcn_rcpf(e + 1.0f);
        return __builtin_fmaf(-2.0f, r, 1.0f);
    };

    unsigned int BfA[12], BfB[12];
    BfA[0] = pkf16(cA0, cA1); BfA[1] = pkf16(cA2, 1.0f);
    BfA[2] = pkf16(1.0f, 0.0f); BfA[3] = 0u;
    BfB[0] = pkf16(cB0, cB1); BfB[1] = pkf16(cB2, 1.0f);
    BfB[2] = pkf16(1.0f, 0.0f); BfB[3] = 0u;

    auto AF = [&](int f) -> f16x8 {
        return ((const f16x8*)sf)[f * 64 + lane];
    };
    auto BFx = [&](const unsigned (&B)[12], int c) -> f16x8 {
        u32x4 t = { B[4 * c + 0], B[4 * c + 1], B[4 * c + 2], B[4 * c + 3] };
        return __builtin_bit_cast(f16x8, t);
    };

    f16x8 F0, F1, F2, F3, F4, F5;

    // ---- layer 0 (K chunk 0: coords + bias + offset cols)
    F0 = AF(0); F1 = AF(1);
    {
        f32x16 D0 = MFMA(F0, BFx(BfA, 0), CZ, 0, 0, 0);
        f32x16 D1 = MFMA(F1, BFx(BfA, 0), CZ, 0, 0, 0);
        ACT(D0, D1, BfA);
    }
    {
        f32x16 D0 = MFMA(F0, BFx(BfB, 0), CZ, 0, 0, 0);
        f32x16 D1 = MFMA(F1, BFx(BfB, 0), CZ, 0, 0, 0);
        ACT(D0, D1, BfB);
    }

    // ---- hidden layers 1..5
    #pragma unroll
    for (int l = 1; l <= 5; ++l) {
        const int fb = 2 + (l - 1) * 6;
        F0 = AF(fb + 0); F1 = AF(fb + 1); F2 = AF(fb + 2);
        F3 = AF(fb + 3); F4 = AF(fb + 4); F5 = AF(fb + 5);
        {
            f16x8 B0 = BFx(BfA, 0), B1 = BFx(BfA, 1), B2 = BFx(BfA, 2);
            f32x16 D0 = MFMA(F0, B0, CZ, 0, 0, 0);
            D0 = MFMA(F1, B1, D0, 0, 0, 0);
            D0 = MFMA(F2, B2, D0, 0, 0, 0);
            f32x16 D1 = MFMA(F3, B0, CZ, 0, 0, 0);
            D1 = MFMA(F4, B1, D1, 0, 0, 0);
            D1 = MFMA(F5, B2, D1, 0, 0, 0);
            ACT(D0, D1, BfA);
        }
        {
            f16x8 B0 = BFx(BfB, 0), B1 = BFx(BfB, 1), B2 = BFx(BfB, 2);
            f32x16 D0 = MFMA(F0, B0, CZ, 0, 0, 0);
            D0 = MFMA(F1, B1, D0, 0, 0, 0);
            D0 = MFMA(F2, B2, D0, 0, 0, 0);
            f32x16 D1 = MFMA(F3, B0, CZ, 0, 0, 0);
            D1 = MFMA(F4, B1, D1, 0, 0, 0);
            D1 = MFMA(F5, B2, D1, 0, 0, 0);
            ACT(D0, D1, BfB);
        }
    }

    // ---- layer 6: [40] -> [3], true scale, no tanh. Rows 0..2 (lane<32).
    F0 = AF(32); F1 = AF(33); F2 = AF(34);
    {
        f32x16 D0 = MFMA(F0, BFx(BfA, 0), CZ, 0, 0, 0);
        D0 = MFMA(F1, BFx(BfA, 1), D0, 0, 0, 0);
        D0 = MFMA(F2, BFx(BfA, 2), D0, 0, 0, 0);
        if (lane < 32 && vA) {
            out[pA * 3 + 0] = D0[0];
            out[pA * 3 + 1] = D0[1];
            out[pA * 3 + 2] = D0[2];
        }
    }
    {
        f32x16 D0 = MFMA(F0, BFx(BfB, 0), CZ, 0, 0, 0);
        D0 = MFMA(F1, BFx(BfB, 1), D0, 0, 0, 0);
        D0 = MFMA(F2, BFx(BfB, 2), D0, 0, 0, 0);
        if (lane < 32 && vB) {
            out[pB * 3 + 0] = D0[0];
            out[pB * 3 + 1] = D0[1];
            out[pB * 3 + 2] = D0[2];
        }
    }
}

extern "C" void kernel_launch(void* const* d_in, const int* in_sizes, int n_in,
                              void* d_out, int out_size, void* d_ws, size_t ws_size,
                              hipStream_t stream)
{
    const float* coords = (const float*)d_in[0];
    const float* W0 = (const float*)d_in[1];  const float* b0 = (const float*)d_in[2];
    const float* W1 = (const float*)d_in[3];  const float* b1 = (const float*)d_in[4];
    const float* W2 = (const float*)d_in[5];  const float* b2 = (const float*)d_in[6];
    const float* W3 = (const float*)d_in[7];  const float* b3 = (const float*)d_in[8];
    const float* W4 = (const float*)d_in[9];  const float* b4 = (const float*)d_in[10];
    const float* W5 = (const float*)d_in[11]; const float* b5 = (const float*)d_in[12];
    const float* W6 = (const float*)d_in[13]; const float* b6 = (const float*)d_in[14];
    float* out = (float*)d_out;

    unsigned short* frags = (unsigned short*)d_ws;                      // 35840 B
    unsigned* table = (unsigned*)((char*)d_ws + NFRAG * 1024);          // 900 B

    const int npts = in_sizes[0] / 3;

    const int prep_threads = NFRAG * 64 + TABN;
    prep_frags<<<(prep_threads + 255) / 256, 256, 0, stream>>>(
        W0, b0, W1, b1, W2, b2, W3, b3, W4, b4, W5, b5, W6, b6, frags, table);

    const int blocks = (npts + 511) / 512;   // 512 points per block (8 waves x 64)
    mlp_mfma<<<blocks, 512, 0, stream>>>(coords, frags, table, out, npts);
}